// Round 1
// baseline (962.870 us; speedup 1.0000x reference)
//
#include <hip/hip_runtime.h>
#include <cstdint>
#include <cmath>

#define B_ 2
#define C_ 64
#define H_ 128
#define W_ 240
#define HW_ (H_*W_)
#define DG_ 8
#define K_ 9
#define OFF_CH 144
#define MASK_CH 72
#define ALIGNED_SZ (B_*C_*HW_)   /* 3932160 floats */

// ---------------------------------------------------------------------------
// Kernel 1: conv 3x3 (Cin=128 = concat[nbr,ref], Cout=64) + LeakyReLU(0.1)
// grid (15,8,B*4)  block 256 (16x16 pixel tile, 16 out-channels per z-slice)
// ---------------------------------------------------------------------------
__global__ __launch_bounds__(256) void conv1_lrelu(
    const float* __restrict__ nbr, const float* __restrict__ ref,
    const float* __restrict__ w1, const float* __restrict__ b1,
    float* __restrict__ hbuf)
{
    const int bx = blockIdx.x, by = blockIdx.y;
    const int b   = blockIdx.z >> 2;
    const int ocs = (blockIdx.z & 3) << 4;
    const int tx = threadIdx.x & 15, ty = threadIdx.x >> 4;
    const int x = (bx << 4) + tx, y = (by << 4) + ty;

    __shared__ float s_in[16][324];                  // 16 ch x 18x18
    __shared__ __align__(16) float s_w[16 * 16 * 12]; // [cin][oc][12(pad 9)]

    float acc[16];
#pragma unroll
    for (int i = 0; i < 16; ++i) acc[i] = b1[ocs + i];

    for (int chunk = 0; chunk < 8; ++chunk) {
        const int cin0 = chunk << 4;
        const float* src = (cin0 < 64)
            ? nbr + ((size_t)b * C_ + cin0) * HW_
            : ref + ((size_t)b * C_ + (cin0 - 64)) * HW_;

        for (int idx = threadIdx.x; idx < 16 * 324; idx += 256) {
            int c = idx / 324, r = idx - c * 324;
            int iy = r / 18, ix = r - iy * 18;
            int gy = (by << 4) + iy - 1, gx = (bx << 4) + ix - 1;
            float v = 0.f;
            if ((unsigned)gy < (unsigned)H_ && (unsigned)gx < (unsigned)W_)
                v = src[(size_t)c * HW_ + gy * W_ + gx];
            s_in[c][r] = v;
        }
        for (int idx = threadIdx.x; idx < 16 * 16 * 9; idx += 256) {
            int c = idx / 144, r = idx - c * 144;
            int oc = r / 9, tap = r - oc * 9;
            s_w[(c * 16 + oc) * 12 + tap] =
                w1[(((size_t)(ocs + oc)) * 128 + cin0 + c) * 9 + tap];
        }
        __syncthreads();

        for (int c = 0; c < 16; ++c) {
            float v[9];
#pragma unroll
            for (int dy = 0; dy < 3; ++dy)
#pragma unroll
                for (int dx = 0; dx < 3; ++dx)
                    v[dy * 3 + dx] = s_in[c][(ty + dy) * 18 + tx + dx];
#pragma unroll
            for (int oc = 0; oc < 16; ++oc) {
                const float* wp = &s_w[(c * 16 + oc) * 12];
                float4 wa = *(const float4*)wp;
                float4 wb = *(const float4*)(wp + 4);
                float wc = wp[8];
                acc[oc] += v[0] * wa.x + v[1] * wa.y + v[2] * wa.z + v[3] * wa.w
                         + v[4] * wb.x + v[5] * wb.y + v[6] * wb.z + v[7] * wb.w
                         + v[8] * wc;
            }
        }
        __syncthreads();
    }
#pragma unroll
    for (int oc = 0; oc < 16; ++oc) {
        float v = acc[oc];
        v = (v >= 0.f) ? v : 0.1f * v;
        hbuf[(((size_t)b * C_ + ocs + oc) * H_ + y) * W_ + x] = v;
    }
}

// ---------------------------------------------------------------------------
// Kernel 2: conv 3x3 (Cin=64, Cout=216); ch<144 -> offset region of d_out,
// ch>=144 -> sigmoid -> mask buffer.  grid (15,8,B*9), 24 oc per z-slice.
// ---------------------------------------------------------------------------
__global__ __launch_bounds__(256) void conv2_split(
    const float* __restrict__ hbuf,
    const float* __restrict__ w2, const float* __restrict__ b2,
    float* __restrict__ off_out, float* __restrict__ maskbuf)
{
    const int bx = blockIdx.x, by = blockIdx.y;
    const int b   = blockIdx.z / 9;
    const int ocs = (blockIdx.z % 9) * 24;
    const int tx = threadIdx.x & 15, ty = threadIdx.x >> 4;
    const int x = (bx << 4) + tx, y = (by << 4) + ty;

    __shared__ float s_in[16][324];
    __shared__ __align__(16) float s_w[16 * 24 * 12];

    float acc[24];
#pragma unroll
    for (int i = 0; i < 24; ++i) acc[i] = b2[ocs + i];

    for (int chunk = 0; chunk < 4; ++chunk) {
        const int cin0 = chunk << 4;
        const float* src = hbuf + ((size_t)b * C_ + cin0) * HW_;

        for (int idx = threadIdx.x; idx < 16 * 324; idx += 256) {
            int c = idx / 324, r = idx - c * 324;
            int iy = r / 18, ix = r - iy * 18;
            int gy = (by << 4) + iy - 1, gx = (bx << 4) + ix - 1;
            float v = 0.f;
            if ((unsigned)gy < (unsigned)H_ && (unsigned)gx < (unsigned)W_)
                v = src[(size_t)c * HW_ + gy * W_ + gx];
            s_in[c][r] = v;
        }
        for (int idx = threadIdx.x; idx < 16 * 24 * 9; idx += 256) {
            int c = idx / 216, r = idx - c * 216;
            int oc = r / 9, tap = r - oc * 9;
            s_w[(c * 24 + oc) * 12 + tap] =
                w2[(((size_t)(ocs + oc)) * 64 + cin0 + c) * 9 + tap];
        }
        __syncthreads();

        for (int c = 0; c < 16; ++c) {
            float v[9];
#pragma unroll
            for (int dy = 0; dy < 3; ++dy)
#pragma unroll
                for (int dx = 0; dx < 3; ++dx)
                    v[dy * 3 + dx] = s_in[c][(ty + dy) * 18 + tx + dx];
#pragma unroll
            for (int oc = 0; oc < 24; ++oc) {
                const float* wp = &s_w[(c * 24 + oc) * 12];
                float4 wa = *(const float4*)wp;
                float4 wb = *(const float4*)(wp + 4);
                float wc = wp[8];
                acc[oc] += v[0] * wa.x + v[1] * wa.y + v[2] * wa.z + v[3] * wa.w
                         + v[4] * wb.x + v[5] * wb.y + v[6] * wb.z + v[7] * wb.w
                         + v[8] * wc;
            }
        }
        __syncthreads();
    }
#pragma unroll
    for (int oc = 0; oc < 24; ++oc) {
        const int co = ocs + oc;
        float v = acc[oc];
        if (co < 144) {
            off_out[(((size_t)b * OFF_CH + co) * H_ + y) * W_ + x] = v;
        } else {
            maskbuf[(((size_t)b * MASK_CH + (co - 144)) * H_ + y) * W_ + x] =
                1.f / (1.f + expf(-v));
        }
    }
}

// ---------------------------------------------------------------------------
// Kernel 3: modulated deformable conv.  grid (15,8,B) block 256, one pixel
// per thread, all 64 output channels accumulated; weights LDS-staged as
// [ci(16)][k(9)][oc(64)] per 16-input-channel chunk (2 deform groups/chunk).
// ---------------------------------------------------------------------------
__global__ __launch_bounds__(256) void dconv_kernel(
    const float* __restrict__ xin,      // nbr_fea
    const float* __restrict__ offs,     // d_out + ALIGNED_SZ  [B,144,H,W]
    const float* __restrict__ maskbuf,  // [B,72,H,W], sigmoid applied
    const float* __restrict__ wd, const float* __restrict__ bd,
    float* __restrict__ outp)
{
    const int bx = blockIdx.x, by = blockIdx.y, b = blockIdx.z;
    const int tx = threadIdx.x & 15, ty = threadIdx.x >> 4;
    const int x = (bx << 4) + tx, y = (by << 4) + ty;
    const size_t pix = (size_t)y * W_ + x;

    __shared__ __align__(16) float s_w[16 * 9 * 64];   // 36 KB

    float acc[64];
#pragma unroll
    for (int i = 0; i < 64; ++i) acc[i] = bd[i];

    for (int chunk = 0; chunk < 4; ++chunk) {
        const int cin0 = chunk << 4;
        // stage wd transposed: s_w[(ci*9+k)*64+oc] = wd[(oc*64+cin0+ci)*9+k]
        for (int idx = threadIdx.x; idx < 16 * 9 * 64; idx += 256) {
            int ci = idx / 576, r = idx - ci * 576;
            int k = r >> 6, oc = r & 63;
            s_w[idx] = wd[((size_t)oc * 64 + cin0 + ci) * 9 + k];
        }
        __syncthreads();

        for (int dgl = 0; dgl < 2; ++dgl) {
            const int dg = (chunk << 1) + dgl;
            const float* base = xin + ((size_t)b * C_ + dg * 8) * HW_;
            for (int k = 0; k < 9; ++k) {
                const int ky = k / 3 - 1, kx = k % 3 - 1;
                float dy = offs[((size_t)b * OFF_CH + dg * 18 + k) * HW_ + pix];
                float dx = offs[((size_t)b * OFF_CH + dg * 18 + 9 + k) * HW_ + pix];
                float m  = maskbuf[((size_t)b * MASK_CH + dg * 9 + k) * HW_ + pix];

                float py = (float)(y + ky) + dy;
                float px = (float)(x + kx) + dx;
                float y0f = floorf(py), x0f = floorf(px);
                float wy = py - y0f, wx = px - x0f;
                int y0 = (int)y0f, x0 = (int)x0f;

                const bool y0v = (unsigned)y0 < (unsigned)H_;
                const bool y1v = (unsigned)(y0 + 1) < (unsigned)H_;
                const bool x0v = (unsigned)x0 < (unsigned)W_;
                const bool x1v = (unsigned)(x0 + 1) < (unsigned)W_;

                float w00 = (1.f - wy) * (1.f - wx) * m; if (!(y0v && x0v)) w00 = 0.f;
                float w01 = (1.f - wy) * wx        * m; if (!(y0v && x1v)) w01 = 0.f;
                float w10 = wy        * (1.f - wx) * m; if (!(y1v && x0v)) w10 = 0.f;
                float w11 = wy        * wx         * m; if (!(y1v && x1v)) w11 = 0.f;

                // clamped gather addresses (always in-bounds; weight zeroed)
                int yc0 = min(max(y0, 0), H_ - 1), yc1 = min(max(y0 + 1, 0), H_ - 1);
                int xc0 = min(max(x0, 0), W_ - 1), xc1 = min(max(x0 + 1, 0), W_ - 1);
                const int p00 = yc0 * W_ + xc0, p01 = yc0 * W_ + xc1;
                const int p10 = yc1 * W_ + xc0, p11 = yc1 * W_ + xc1;

                for (int cl = 0; cl < 8; ++cl) {
                    const int ci = (dgl << 3) + cl;
                    const float* cb = base + (size_t)cl * HW_;
                    float s = cb[p00] * w00 + cb[p01] * w01
                            + cb[p10] * w10 + cb[p11] * w11;
                    const float* wp = &s_w[(ci * 9 + k) * 64];
#pragma unroll
                    for (int oc = 0; oc < 64; oc += 4) {
                        float4 w4 = *(const float4*)(wp + oc);
                        acc[oc]     += s * w4.x;
                        acc[oc + 1] += s * w4.y;
                        acc[oc + 2] += s * w4.z;
                        acc[oc + 3] += s * w4.w;
                    }
                }
            }
        }
        __syncthreads();
    }

#pragma unroll
    for (int oc = 0; oc < 64; ++oc)
        outp[(((size_t)b * C_ + oc) * H_ + y) * W_ + x] = acc[oc];
}

// ---------------------------------------------------------------------------
extern "C" void kernel_launch(void* const* d_in, const int* in_sizes, int n_in,
                              void* d_out, int out_size, void* d_ws, size_t ws_size,
                              hipStream_t stream)
{
    const float* nbr = (const float*)d_in[0];
    const float* ref = (const float*)d_in[1];
    const float* w1  = (const float*)d_in[2];
    const float* b1  = (const float*)d_in[3];
    const float* w2  = (const float*)d_in[4];
    const float* b2  = (const float*)d_in[5];
    const float* wd  = (const float*)d_in[6];
    const float* bd  = (const float*)d_in[7];

    float* out     = (float*)d_out;
    float* off_out = out + ALIGNED_SZ;          // offset_curr region of d_out

    float* ws      = (float*)d_ws;
    float* hbuf    = ws;                        // B*C*H*W   = 3,932,160 f32
    float* maskbuf = ws + (size_t)ALIGNED_SZ;   // B*72*H*W  = 4,423,680 f32

    dim3 blk(256, 1, 1);
    conv1_lrelu<<<dim3(15, 8, B_ * 4), blk, 0, stream>>>(nbr, ref, w1, b1, hbuf);
    conv2_split<<<dim3(15, 8, B_ * 9), blk, 0, stream>>>(hbuf, w2, b2, off_out, maskbuf);
    dconv_kernel<<<dim3(15, 8, B_), blk, 0, stream>>>(nbr, off_out, maskbuf, wd, bd, out);
}